// Round 1
// baseline (6394.875 us; speedup 1.0000x reference)
//
#include <hip/hip_runtime.h>
#include <stdint.h>

#define B_ 64
#define T_ 2048
#define H_ 128
#define G_ 512
#define NL 3
#define OUT_ 10

typedef __attribute__((ext_vector_type(8))) short bf16x8;
typedef __attribute__((ext_vector_type(4))) float f32x4;

__device__ __forceinline__ float bf2f(uint16_t u){
  union { uint32_t u; float f; } v; v.u = ((uint32_t)u) << 16; return v.f;
}
__device__ __forceinline__ uint16_t f2bf(float f){
  union { float f; uint32_t u; } v; v.f = f;
  uint32_t u = v.u;
  uint32_t r = (u + 0x7FFFu + ((u >> 16) & 1u)) >> 16;
  return (uint16_t)r;
}
__device__ __forceinline__ float sigm(float x){
  return __builtin_amdgcn_rcpf(1.0f + __builtin_amdgcn_exp2f(x * -1.44269504f));
}
__device__ __forceinline__ float tanh_(float x){
  float e = __builtin_amdgcn_exp2f(x * 2.88539008f);
  return 1.0f - 2.0f * __builtin_amdgcn_rcpf(e + 1.0f);
}

// ---------------------------------------------------------------- prep
__global__ void prep_kernel(const float* __restrict__ x,
                            const float* __restrict__ wih, const float* __restrict__ whh,
                            const float* __restrict__ bih, const float* __restrict__ bhh,
                            uint16_t* __restrict__ A0, uint16_t* __restrict__ WIH,
                            uint16_t* __restrict__ WHH, float* __restrict__ BSUM){
  int stride = gridDim.x * blockDim.x;
  int g0 = blockIdx.x * blockDim.x + threadIdx.x;
  for (int i = g0; i < B_*T_*H_; i += stride) A0[i] = f2bf(x[i]);
  for (int i = g0; i < NL*G_*H_; i += stride){ WIH[i] = f2bf(wih[i]); WHH[i] = f2bf(whh[i]); }
  for (int i = g0; i < NL*G_; i += stride) BSUM[i] = bih[i] + bhh[i];
}

// ---------------------------------------------------------------- projection GEMM
// GX[m][n] = sum_k Ain[m][k] * W[n][k]   (M=131072, N=512, K=128), bf16 in/out, fp32 acc
__global__ __launch_bounds__(512) void proj_kernel(const uint16_t* __restrict__ Ain,
      const uint16_t* __restrict__ W, uint16_t* __restrict__ GX){
  __shared__ uint16_t Alds[16*128];
  __shared__ uint16_t Olds[16*512];
  int tid = threadIdx.x;
  int w = tid >> 6, l = tid & 63, lo = l & 15, hi = l >> 4;
  int n0 = w * 64;
  bf16x8 bw[4][4];
#pragma unroll
  for (int nt = 0; nt < 4; ++nt)
#pragma unroll
    for (int kc = 0; kc < 4; ++kc){
      int n = n0 + nt*16 + lo;
      bw[nt][kc] = *(const bf16x8*)(W + n*H_ + kc*32 + hi*8);
    }
  for (int m = blockIdx.x; m < (B_*T_)/16; m += gridDim.x){
    if (tid < 256){
      int row = tid >> 4, c16 = tid & 15;
      f32x4 v = *(const f32x4*)(Ain + (size_t)(m*16 + row)*H_ + c16*8);
      *(f32x4*)((char*)Alds + row*256 + ((c16*16) ^ ((row & 7) << 4))) = v;
    }
    __syncthreads();
    bf16x8 af[4];
#pragma unroll
    for (int kc = 0; kc < 4; ++kc)
      af[kc] = *(const bf16x8*)((const char*)Alds + lo*256 + (((kc*64) + hi*16) ^ ((lo & 7) << 4)));
    f32x4 acc[4];
#pragma unroll
    for (int nt = 0; nt < 4; ++nt)
#pragma unroll
      for (int r = 0; r < 4; ++r) acc[nt][r] = 0.0f;
#pragma unroll
    for (int kc = 0; kc < 4; ++kc)
#pragma unroll
      for (int nt = 0; nt < 4; ++nt)
        acc[nt] = __builtin_amdgcn_mfma_f32_16x16x32_bf16(af[kc], bw[nt][kc], acc[nt], 0, 0, 0);
#pragma unroll
    for (int nt = 0; nt < 4; ++nt)
#pragma unroll
      for (int r = 0; r < 4; ++r){
        int row = hi*4 + r, col = n0 + nt*16 + lo;
        Olds[row*G_ + col] = f2bf(acc[nt][r]);
      }
    __syncthreads();
    {
      const char* src = (const char*)Olds + tid*32;
      char* dst = (char*)GX + (size_t)m*16*G_*2 + (size_t)tid*32;
      *(f32x4*)dst = *(const f32x4*)src;
      *(f32x4*)(dst+16) = *(const f32x4*)(src+16);
    }
    __syncthreads();
  }
}

// ---------------------------------------------------------------- scan
// 16 WGs x 512 thr. WG owns 4 batches. W_hh B-frags in registers; h ping-pong in LDS.
#define SCAN_STEP(tcur, GXR, RB, WB) do { \
    bf16x8 af[4]; \
    _Pragma("unroll") \
    for (int kc = 0; kc < 4; ++kc) \
      af[kc] = *(const bf16x8*)((const char*)(RB) + lo*256 + (((kc*64) + hi*16) ^ ((lo & 7) << 4))); \
    f32x4 acc[4]; \
    _Pragma("unroll") \
    for (int g = 0; g < 4; ++g){ \
      _Pragma("unroll") \
      for (int r = 0; r < 4; ++r) acc[g][r] = bf2f(GXR[g*4+r]); \
    } \
    _Pragma("unroll") \
    for (int g = 0; g < 4; ++g){ \
      _Pragma("unroll") \
      for (int r = 0; r < 4; ++r) GXR[g*4+r] = gptr[(size_t)r*T_*G_ + g*128]; \
    } \
    gptr += G_; \
    _Pragma("unroll") \
    for (int kc = 0; kc < 4; ++kc){ \
      _Pragma("unroll") \
      for (int g = 0; g < 4; ++g) \
        acc[g] = __builtin_amdgcn_mfma_f32_16x16x32_bf16(af[kc], bw[g][kc], acc[g], 0, 0, 0); \
    } \
    uint16_t hbf[4]; float hval[4]; \
    _Pragma("unroll") \
    for (int r = 0; r < 4; ++r){ \
      float xi = acc[0][r] + bias[0]; \
      float xf = acc[1][r] + bias[1]; \
      float xg = acc[2][r] + bias[2]; \
      float xo = acc[3][r] + bias[3]; \
      float iv = sigm(xi), fv = sigm(xf), gv = tanh_(xg), ov = sigm(xo); \
      c[r] = fv * c[r] + iv * gv; \
      float th = tanh_(c[r]); \
      hval[r] = ov * th; \
      hbf[r] = f2bf(hval[r]); \
    } \
    _Pragma("unroll") \
    for (int r = 0; r < 4; ++r){ \
      int row = hi*4 + r; \
      *(uint16_t*)((char*)(WB) + row*256 + ((j*2) ^ ((row & 7) << 4))) = hbf[r]; \
    } \
    if (!last){ \
      if (hi == 0){ \
        _Pragma("unroll") \
        for (int r = 0; r < 4; ++r) \
          Aout[((size_t)(b0+r)*T_ + (tcur))*H_ + j] = hbf[r]; \
      } \
    } else if ((tcur) == T_-1 && hi == 0){ \
      _Pragma("unroll") \
      for (int r = 0; r < 4; ++r) hlast[(b0+r)*H_ + j] = hval[r]; \
    } \
    __syncthreads(); \
  } while(0)

__global__ __launch_bounds__(512) void scan_kernel(const uint16_t* __restrict__ GX,
      const uint16_t* __restrict__ Whh, const float* __restrict__ bsum,
      uint16_t* __restrict__ Aout, float* __restrict__ hlast, int last){
  __shared__ uint16_t hb0[16*128];
  __shared__ uint16_t hb1[16*128];
  int tid = threadIdx.x;
  int w = tid >> 6, l = tid & 63, lo = l & 15, hi = l >> 4;
  int j = w*16 + lo;
  int b0 = blockIdx.x * 4;
  for (int i = tid; i < 16*128; i += 512) hb0[i] = 0;
  bf16x8 bw[4][4];
#pragma unroll
  for (int g = 0; g < 4; ++g)
#pragma unroll
    for (int kc = 0; kc < 4; ++kc){
      int n = g*128 + j;
      bw[g][kc] = *(const bf16x8*)(Whh + n*H_ + kc*32 + hi*8);
    }
  float bias[4];
#pragma unroll
  for (int g = 0; g < 4; ++g) bias[g] = bsum[g*128 + j];
  float c[4] = {0.f, 0.f, 0.f, 0.f};
  const uint16_t* gptr = GX + (size_t)b0 * T_ * G_ + j;
  uint16_t ga[16], gb[16], gc[16], gd[16];
#pragma unroll
  for (int g = 0; g < 4; ++g)
#pragma unroll
    for (int r = 0; r < 4; ++r) ga[g*4+r] = gptr[(size_t)r*T_*G_ + g*128];
  gptr += G_;
#pragma unroll
  for (int g = 0; g < 4; ++g)
#pragma unroll
    for (int r = 0; r < 4; ++r) gb[g*4+r] = gptr[(size_t)r*T_*G_ + g*128];
  gptr += G_;
#pragma unroll
  for (int g = 0; g < 4; ++g)
#pragma unroll
    for (int r = 0; r < 4; ++r) gc[g*4+r] = gptr[(size_t)r*T_*G_ + g*128];
  gptr += G_;
#pragma unroll
  for (int g = 0; g < 4; ++g)
#pragma unroll
    for (int r = 0; r < 4; ++r) gd[g*4+r] = gptr[(size_t)r*T_*G_ + g*128];
  gptr += G_;
  __syncthreads();

  for (int t = 0; t < T_; t += 4){
    SCAN_STEP(t,   ga, hb0, hb1);
    SCAN_STEP(t+1, gb, hb1, hb0);
    SCAN_STEP(t+2, gc, hb0, hb1);
    SCAN_STEP(t+3, gd, hb1, hb0);
  }
}

// ---------------------------------------------------------------- final MLP (fp32)
__global__ void mlp_kernel(const float* __restrict__ hlast,
    const float* __restrict__ w1, const float* __restrict__ b1,
    const float* __restrict__ w2, const float* __restrict__ b2,
    const float* __restrict__ w3, const float* __restrict__ b3,
    float* __restrict__ out){
  int b = blockIdx.x, t = threadIdx.x;
  __shared__ float sh[128];
  __shared__ float s1[64];
  __shared__ float s2[32];
  sh[t] = hlast[b*H_ + t];
  sh[t+64] = hlast[b*H_ + t + 64];
  __syncthreads();
  if (t < 64){
    float d = b1[t];
    for (int k = 0; k < 128; ++k) d += sh[k]*w1[t*128+k];
    s1[t] = d;
  }
  __syncthreads();
  if (t < 32){
    float d = b2[t];
    for (int k = 0; k < 64; ++k) d += s1[k]*w2[t*64+k];
    s2[t] = d;
  }
  __syncthreads();
  if (t < 10){
    float d = b3[t];
    for (int k = 0; k < 32; ++k) d += s2[k]*w3[t*32+k];
    out[b*OUT_ + t] = d;
  }
}

// ---------------------------------------------------------------- launch
extern "C" void kernel_launch(void* const* d_in, const int* in_sizes, int n_in,
                              void* d_out, int out_size, void* d_ws, size_t ws_size,
                              hipStream_t stream){
  const float* x   = (const float*)d_in[0];
  const float* wih = (const float*)d_in[1];
  const float* whh = (const float*)d_in[2];
  const float* bih = (const float*)d_in[3];
  const float* bhh = (const float*)d_in[4];
  const float* w1  = (const float*)d_in[5];
  const float* b1  = (const float*)d_in[6];
  const float* w2  = (const float*)d_in[7];
  const float* b2  = (const float*)d_in[8];
  const float* w3  = (const float*)d_in[9];
  const float* b3  = (const float*)d_in[10];
  float* out = (float*)d_out;

  char* ws = (char*)d_ws;
  uint16_t* A0   = (uint16_t*)(ws);                     // B*T*H bf16   = 33554432 B
  uint16_t* A1   = (uint16_t*)(ws + 33554432);          // B*T*H bf16   = 33554432 B
  uint16_t* GX   = (uint16_t*)(ws + 67108864);          // B*T*G bf16   = 134217728 B
  uint16_t* WIH  = (uint16_t*)(ws + 201326592);         // 3*512*128 bf16
  uint16_t* WHH  = (uint16_t*)(ws + 201719808);         // 3*512*128 bf16
  float*    BSUM = (float*)   (ws + 202113024);         // 3*512 f32
  float*    HL   = (float*)   (ws + 202119168);         // 64*128 f32

  prep_kernel<<<2048, 256, 0, stream>>>(x, wih, whh, bih, bhh, A0, WIH, WHH, BSUM);

  const uint16_t* ain[3] = {A0, A1, A0};
  uint16_t*       aout[3] = {A1, A0, A1};
  for (int lyr = 0; lyr < 3; ++lyr){
    proj_kernel<<<512, 512, 0, stream>>>(ain[lyr], WIH + lyr*G_*H_, GX);
    scan_kernel<<<16, 512, 0, stream>>>(GX, WHH + lyr*G_*H_, BSUM + lyr*G_,
                                        aout[lyr], HL, lyr == 2 ? 1 : 0);
  }
  mlp_kernel<<<B_, 64, 0, stream>>>(HL, w1, b1, w2, b2, w3, b3, out);
}

// Round 2
// 6329.070 us; speedup vs baseline: 1.0104x; 1.0104x over previous
//
#include <hip/hip_runtime.h>
#include <stdint.h>

#define B_ 64
#define T_ 2048
#define H_ 128
#define G_ 512
#define NL 3
#define OUT_ 10

typedef __attribute__((ext_vector_type(8))) short bf16x8;
typedef __attribute__((ext_vector_type(4))) short bf16x4;
typedef __attribute__((ext_vector_type(4))) float f32x4;

__device__ __forceinline__ float bf2f(uint16_t u){
  union { uint32_t u; float f; } v; v.u = ((uint32_t)u) << 16; return v.f;
}
__device__ __forceinline__ uint16_t f2bf(float f){
  union { float f; uint32_t u; } v; v.f = f;
  uint32_t u = v.u;
  uint32_t r = (u + 0x7FFFu + ((u >> 16) & 1u)) >> 16;
  return (uint16_t)r;
}
__device__ __forceinline__ float sigm(float x){
  return __builtin_amdgcn_rcpf(1.0f + __builtin_amdgcn_exp2f(x * -1.44269504f));
}
__device__ __forceinline__ float tanh_(float x){
  float e = __builtin_amdgcn_exp2f(x * 2.88539008f);
  return 1.0f - 2.0f * __builtin_amdgcn_rcpf(e + 1.0f);
}

// Barrier WITHOUT the vmcnt(0) drain: LDS ordering only. Prefetched global
// loads / output stores stay in flight across steps.
__device__ __forceinline__ void wg_barrier(){
  asm volatile("s_waitcnt lgkmcnt(0)" ::: "memory");
  __builtin_amdgcn_sched_barrier(0);
  __builtin_amdgcn_s_barrier();
  __builtin_amdgcn_sched_barrier(0);
}

// ---------------------------------------------------------------- prep
__global__ void prep_kernel(const float* __restrict__ x,
                            const float* __restrict__ wih, const float* __restrict__ whh,
                            const float* __restrict__ bih, const float* __restrict__ bhh,
                            uint16_t* __restrict__ A0, uint16_t* __restrict__ WIH,
                            uint16_t* __restrict__ WHH, float* __restrict__ BSUM){
  int stride = gridDim.x * blockDim.x;
  int g0 = blockIdx.x * blockDim.x + threadIdx.x;
  for (int i = g0; i < B_*T_*H_; i += stride) A0[i] = f2bf(x[i]);
  for (int i = g0; i < NL*G_*H_; i += stride){ WIH[i] = f2bf(wih[i]); WHH[i] = f2bf(whh[i]); }
  for (int i = g0; i < NL*G_; i += stride) BSUM[i] = bih[i] + bhh[i];
}

// ---------------------------------------------------------------- projection GEMM
// Computes gx[b][t][n] = sum_k Ain[b][t][k] * W[n][k], writes into the
// scan-friendly layout GXb[(((b>>2)*T + t)*4 + g)*512 + j*4 + (b&3)],
// where n = g*128 + j.  (M=131072, N=512, K=128), bf16 in, fp32 acc.
__global__ __launch_bounds__(512) void proj_kernel(const uint16_t* __restrict__ Ain,
      const uint16_t* __restrict__ W, uint16_t* __restrict__ GXb){
  __shared__ uint16_t Alds[16*128];
  int tid = threadIdx.x;
  int w = tid >> 6, l = tid & 63, lo = l & 15, hi = l >> 4;
  int n0 = w * 64;
  bf16x8 bw[4][4];
#pragma unroll
  for (int nt = 0; nt < 4; ++nt)
#pragma unroll
    for (int kc = 0; kc < 4; ++kc){
      int n = n0 + nt*16 + lo;
      bw[nt][kc] = *(const bf16x8*)(W + n*H_ + kc*32 + hi*8);
    }
  for (int m = blockIdx.x; m < (B_*T_)/16; m += gridDim.x){
    if (tid < 256){
      int row = tid >> 4, c16 = tid & 15;
      f32x4 v = *(const f32x4*)(Ain + (size_t)(m*16 + row)*H_ + c16*8);
      *(f32x4*)((char*)Alds + row*256 + ((c16*16) ^ ((row & 7) << 4))) = v;
    }
    __syncthreads();
    bf16x8 af[4];
#pragma unroll
    for (int kc = 0; kc < 4; ++kc)
      af[kc] = *(const bf16x8*)((const char*)Alds + lo*256 + (((kc*64) + hi*16) ^ ((lo & 7) << 4)));
    f32x4 acc[4];
#pragma unroll
    for (int nt = 0; nt < 4; ++nt)
#pragma unroll
      for (int r = 0; r < 4; ++r) acc[nt][r] = 0.0f;
#pragma unroll
    for (int kc = 0; kc < 4; ++kc)
#pragma unroll
      for (int nt = 0; nt < 4; ++nt)
        acc[nt] = __builtin_amdgcn_mfma_f32_16x16x32_bf16(af[kc], bw[nt][kc], acc[nt], 0, 0, 0);
    int b  = m >> 7;            // T/16 = 128 tiles per batch
    int t0 = (m & 127) << 4;
    size_t wgbase = (size_t)(b >> 2) * T_;
    int rb = b & 3;
#pragma unroll
    for (int nt = 0; nt < 4; ++nt){
      int col = n0 + nt*16 + lo;
      int g = col >> 7, j = col & 127;
#pragma unroll
      for (int r = 0; r < 4; ++r){
        int t = t0 + hi*4 + r;
        GXb[((wgbase + t)*4 + g)*512 + j*4 + rb] = f2bf(acc[nt][r]);
      }
    }
    __syncthreads();
  }
}

// ---------------------------------------------------------------- scan
// 16 WGs x 512 thr. WG owns 4 batches (rows 0..3 of the 16-row MFMA tile;
// rows 4..15 are bounded garbage). W_hh B-frags in registers; h ping-pong in
// LDS; gx prefetched 4 steps ahead (4 x 8B loads/step, never drained).
#define PF(GXR, tnext) do { \
    _Pragma("unroll") \
    for (int g = 0; g < 4; ++g) \
      GXR[g] = *(const bf16x4*)(gbase + ((size_t)(tnext)*4 + g)*512); \
  } while(0)

#define SCAN_STEP(tcur, GXR, RB, WB) do { \
    bf16x8 af[4]; \
    _Pragma("unroll") \
    for (int kc = 0; kc < 4; ++kc) \
      af[kc] = *(const bf16x8*)((const char*)(RB) + lo*256 + (((kc*64) + hi*16) ^ ((lo & 7) << 4))); \
    f32x4 acc[4]; \
    _Pragma("unroll") \
    for (int g = 0; g < 4; ++g){ \
      _Pragma("unroll") \
      for (int r = 0; r < 4; ++r) acc[g][r] = bf2f((uint16_t)GXR[g][r]); \
    } \
    PF(GXR, (tcur) + 4); \
    _Pragma("unroll") \
    for (int kc = 0; kc < 4; ++kc){ \
      _Pragma("unroll") \
      for (int g = 0; g < 4; ++g) \
        acc[g] = __builtin_amdgcn_mfma_f32_16x16x32_bf16(af[kc], bw[g][kc], acc[g], 0, 0, 0); \
    } \
    uint16_t hbf[4]; float hval[4]; \
    _Pragma("unroll") \
    for (int r = 0; r < 4; ++r){ \
      float xi = acc[0][r] + bias[0]; \
      float xf = acc[1][r] + bias[1]; \
      float xg = acc[2][r] + bias[2]; \
      float xo = acc[3][r] + bias[3]; \
      float iv = sigm(xi), fv = sigm(xf), gv = tanh_(xg), ov = sigm(xo); \
      c[r] = fv * c[r] + iv * gv; \
      float th = tanh_(c[r]); \
      hval[r] = ov * th; \
      hbf[r] = f2bf(hval[r]); \
    } \
    _Pragma("unroll") \
    for (int r = 0; r < 4; ++r){ \
      int row = hi*4 + r; \
      *(uint16_t*)((char*)(WB) + row*256 + ((j*2) ^ ((row & 7) << 4))) = hbf[r]; \
    } \
    if (!last){ \
      if (hi == 0){ \
        _Pragma("unroll") \
        for (int r = 0; r < 4; ++r) \
          Aout[((size_t)(b0+r)*T_ + (tcur))*H_ + j] = hbf[r]; \
      } \
    } else if ((tcur) == T_-1 && hi == 0){ \
      _Pragma("unroll") \
      for (int r = 0; r < 4; ++r) hlast[(b0+r)*H_ + j] = hval[r]; \
    } \
    wg_barrier(); \
  } while(0)

__global__ __launch_bounds__(512) void scan_kernel(const uint16_t* __restrict__ GXb,
      const uint16_t* __restrict__ Whh, const float* __restrict__ bsum,
      uint16_t* __restrict__ Aout, float* __restrict__ hlast, int last){
  __shared__ uint16_t hb0[16*128];
  __shared__ uint16_t hb1[16*128];
  int tid = threadIdx.x;
  int w = tid >> 6, l = tid & 63, lo = l & 15, hi = l >> 4;
  int j = w*16 + lo;
  int b0 = blockIdx.x * 4;
  for (int i = tid; i < 16*128; i += 512) hb0[i] = 0;
  bf16x8 bw[4][4];
#pragma unroll
  for (int g = 0; g < 4; ++g)
#pragma unroll
    for (int kc = 0; kc < 4; ++kc){
      int n = g*128 + j;
      bw[g][kc] = *(const bf16x8*)(Whh + n*H_ + kc*32 + hi*8);
    }
  float bias[4];
#pragma unroll
  for (int g = 0; g < 4; ++g) bias[g] = bsum[g*128 + j];
  float c[4] = {0.f, 0.f, 0.f, 0.f};
  const uint16_t* gbase = GXb + ((size_t)blockIdx.x * T_ * 4) * 512 + j*4;
  bf16x4 ga[4], gb[4], gc[4], gd[4];
  PF(ga, 0); PF(gb, 1); PF(gc, 2); PF(gd, 3);
  __syncthreads();

  for (int t = 0; t < T_; t += 4){
    SCAN_STEP(t,   ga, hb0, hb1);
    SCAN_STEP(t+1, gb, hb1, hb0);
    SCAN_STEP(t+2, gc, hb0, hb1);
    SCAN_STEP(t+3, gd, hb1, hb0);
  }
}

// ---------------------------------------------------------------- final MLP (fp32)
__global__ void mlp_kernel(const float* __restrict__ hlast,
    const float* __restrict__ w1, const float* __restrict__ b1,
    const float* __restrict__ w2, const float* __restrict__ b2,
    const float* __restrict__ w3, const float* __restrict__ b3,
    float* __restrict__ out){
  int b = blockIdx.x, t = threadIdx.x;
  __shared__ float sh[128];
  __shared__ float s1[64];
  __shared__ float s2[32];
  sh[t] = hlast[b*H_ + t];
  sh[t+64] = hlast[b*H_ + t + 64];
  __syncthreads();
  if (t < 64){
    float d = b1[t];
    for (int k = 0; k < 128; ++k) d += sh[k]*w1[t*128+k];
    s1[t] = d;
  }
  __syncthreads();
  if (t < 32){
    float d = b2[t];
    for (int k = 0; k < 64; ++k) d += s1[k]*w2[t*64+k];
    s2[t] = d;
  }
  __syncthreads();
  if (t < 10){
    float d = b3[t];
    for (int k = 0; k < 32; ++k) d += s2[k]*w3[t*32+k];
    out[b*OUT_ + t] = d;
  }
}

// ---------------------------------------------------------------- launch
extern "C" void kernel_launch(void* const* d_in, const int* in_sizes, int n_in,
                              void* d_out, int out_size, void* d_ws, size_t ws_size,
                              hipStream_t stream){
  const float* x   = (const float*)d_in[0];
  const float* wih = (const float*)d_in[1];
  const float* whh = (const float*)d_in[2];
  const float* bih = (const float*)d_in[3];
  const float* bhh = (const float*)d_in[4];
  const float* w1  = (const float*)d_in[5];
  const float* b1  = (const float*)d_in[6];
  const float* w2  = (const float*)d_in[7];
  const float* b2  = (const float*)d_in[8];
  const float* w3  = (const float*)d_in[9];
  const float* b3  = (const float*)d_in[10];
  float* out = (float*)d_out;

  char* ws = (char*)d_ws;
  uint16_t* A0   = (uint16_t*)(ws);                     // B*T*H bf16   = 33554432 B
  uint16_t* A1   = (uint16_t*)(ws + 33554432);          // B*T*H bf16   = 33554432 B
  uint16_t* GXb  = (uint16_t*)(ws + 67108864);          // B*T*G bf16   = 134217728 B (+64KB pad)
  uint16_t* WIH  = (uint16_t*)(ws + 201392128);         // 3*512*128 bf16
  uint16_t* WHH  = (uint16_t*)(ws + 201785344);         // 3*512*128 bf16
  float*    BSUM = (float*)   (ws + 202178560);         // 3*512 f32
  float*    HL   = (float*)   (ws + 202184704);         // 64*128 f32

  prep_kernel<<<2048, 256, 0, stream>>>(x, wih, whh, bih, bhh, A0, WIH, WHH, BSUM);

  const uint16_t* ain[3] = {A0, A1, A0};
  uint16_t*       aout[3] = {A1, A0, A1};
  for (int lyr = 0; lyr < 3; ++lyr){
    proj_kernel<<<512, 512, 0, stream>>>(ain[lyr], WIH + lyr*G_*H_, GXb);
    scan_kernel<<<16, 512, 0, stream>>>(GXb, WHH + lyr*G_*H_, BSUM + lyr*G_,
                                        aout[lyr], HL, lyr == 2 ? 1 : 0);
  }
  mlp_kernel<<<B_, 64, 0, stream>>>(HL, w1, b1, w2, b2, w3, b3, out);
}

// Round 3
// 4755.009 us; speedup vs baseline: 1.3449x; 1.3310x over previous
//
#include <hip/hip_runtime.h>
#include <stdint.h>

#define B_ 64
#define T_ 2048
#define H_ 128
#define G_ 512
#define NL 3
#define OUT_ 10

typedef __attribute__((ext_vector_type(8))) short bf16x8;
typedef __attribute__((ext_vector_type(4))) short bf16x4;
typedef __attribute__((ext_vector_type(4))) float f32x4;

__device__ __forceinline__ float bf2f(uint16_t u){
  union { uint32_t u; float f; } v; v.u = ((uint32_t)u) << 16; return v.f;
}
__device__ __forceinline__ uint16_t f2bf(float f){
  union { float f; uint32_t u; } v; v.f = f;
  uint32_t u = v.u;
  uint32_t r = (u + 0x7FFFu + ((u >> 16) & 1u)) >> 16;
  return (uint16_t)r;
}
__device__ __forceinline__ float sigm(float x){
  return __builtin_amdgcn_rcpf(1.0f + __builtin_amdgcn_exp2f(x * -1.44269504f));
}
__device__ __forceinline__ float tanh_(float x){
  float e = __builtin_amdgcn_exp2f(x * 2.88539008f);
  return 1.0f - 2.0f * __builtin_amdgcn_rcpf(e + 1.0f);
}

// Barrier WITHOUT the vmcnt(0) drain: LDS ordering only. Prefetched global
// loads / output stores stay in flight across steps.
__device__ __forceinline__ void wg_barrier(){
  asm volatile("s_waitcnt lgkmcnt(0)" ::: "memory");
  __builtin_amdgcn_sched_barrier(0);
  __builtin_amdgcn_s_barrier();
  __builtin_amdgcn_sched_barrier(0);
}

// ---------------------------------------------------------------- prep
__global__ void prep_kernel(const float* __restrict__ x,
                            const float* __restrict__ wih, const float* __restrict__ whh,
                            const float* __restrict__ bih, const float* __restrict__ bhh,
                            uint16_t* __restrict__ A0, uint16_t* __restrict__ WIH,
                            uint16_t* __restrict__ WHH, float* __restrict__ BSUM){
  int stride = gridDim.x * blockDim.x;
  int g0 = blockIdx.x * blockDim.x + threadIdx.x;
  for (int i = g0; i < B_*T_*H_; i += stride) A0[i] = f2bf(x[i]);
  for (int i = g0; i < NL*G_*H_; i += stride){ WIH[i] = f2bf(wih[i]); WHH[i] = f2bf(whh[i]); }
  for (int i = g0; i < NL*G_; i += stride) BSUM[i] = bih[i] + bhh[i];
}

// ---------------------------------------------------------------- projection GEMM
// gx[b][t][n] = sum_k Ain[b][t][k]*W[n][k]; write scan layout
// GXb[((b>>2)*T + t)*2048 + (b&3)*512 + j*4 + g]  where n = g*128 + j.
__global__ __launch_bounds__(512) void proj_kernel(const uint16_t* __restrict__ Ain,
      const uint16_t* __restrict__ W, uint16_t* __restrict__ GXb){
  __shared__ uint16_t Alds[16*128];
  int tid = threadIdx.x;
  int w = tid >> 6, l = tid & 63, lo = l & 15, hi = l >> 4;
  int n0 = w * 64;
  bf16x8 bw[4][4];
#pragma unroll
  for (int nt = 0; nt < 4; ++nt)
#pragma unroll
    for (int kc = 0; kc < 4; ++kc){
      int n = n0 + nt*16 + lo;
      bw[nt][kc] = *(const bf16x8*)(W + n*H_ + kc*32 + hi*8);
    }
  for (int m = blockIdx.x; m < (B_*T_)/16; m += gridDim.x){
    if (tid < 256){
      int row = tid >> 4, c16 = tid & 15;
      f32x4 v = *(const f32x4*)(Ain + (size_t)(m*16 + row)*H_ + c16*8);
      *(f32x4*)((char*)Alds + row*256 + ((c16*16) ^ ((row & 7) << 4))) = v;
    }
    __syncthreads();
    bf16x8 af[4];
#pragma unroll
    for (int kc = 0; kc < 4; ++kc)
      af[kc] = *(const bf16x8*)((const char*)Alds + lo*256 + (((kc*64) + hi*16) ^ ((lo & 7) << 4)));
    f32x4 acc[4];
#pragma unroll
    for (int nt = 0; nt < 4; ++nt)
#pragma unroll
      for (int r = 0; r < 4; ++r) acc[nt][r] = 0.0f;
#pragma unroll
    for (int kc = 0; kc < 4; ++kc)
#pragma unroll
      for (int nt = 0; nt < 4; ++nt)
        acc[nt] = __builtin_amdgcn_mfma_f32_16x16x32_bf16(af[kc], bw[nt][kc], acc[nt], 0, 0, 0);
    int b  = m >> 7;            // 128 tiles per batch
    int t0 = (m & 127) << 4;
    size_t base = ((size_t)(b >> 2) * T_) * 2048 + (size_t)(b & 3) * 512;
#pragma unroll
    for (int nt = 0; nt < 4; ++nt){
      int n = n0 + nt*16 + lo;
      int g = n >> 7, jj = n & 127;
#pragma unroll
      for (int r = 0; r < 4; ++r){
        int t = t0 + hi*4 + r;
        GXb[base + (size_t)t*2048 + jj*4 + g] = f2bf(acc[nt][r]);
      }
    }
    __syncthreads();
  }
}

// ---------------------------------------------------------------- scan
// 16 WGs x 512 thr, 4 real batches per WG.
// Phase A: 4-row h tile -> MFMA (af loaded only by lo<4 lanes, rows 4..15 are
//          zero registers); hi==0 lanes spill pre-acts to PrL[g][j][b].
// Phase B: lane (b=tid>>7, j=tid&127) does ONE gate eval: reads PrL, adds
//          prefetched gx + bias, writes h (LDS + global).
#define STEP(tcur, GXR) do { \
    bf16x8 af0 = Z8, af1 = Z8, af2 = Z8, af3 = Z8; \
    if (lo < 4){ \
      af0 = *(const bf16x8*)(hbase + afo0); \
      af1 = *(const bf16x8*)(hbase + afo1); \
      af2 = *(const bf16x8*)(hbase + afo2); \
      af3 = *(const bf16x8*)(hbase + afo3); \
    } \
    f32x4 a0, a1, a2, a3; \
    a0 = __builtin_amdgcn_mfma_f32_16x16x32_bf16(af0, bw[0][0], z4, 0,0,0); \
    a1 = __builtin_amdgcn_mfma_f32_16x16x32_bf16(af0, bw[1][0], z4, 0,0,0); \
    a2 = __builtin_amdgcn_mfma_f32_16x16x32_bf16(af0, bw[2][0], z4, 0,0,0); \
    a3 = __builtin_amdgcn_mfma_f32_16x16x32_bf16(af0, bw[3][0], z4, 0,0,0); \
    a0 = __builtin_amdgcn_mfma_f32_16x16x32_bf16(af1, bw[0][1], a0, 0,0,0); \
    a1 = __builtin_amdgcn_mfma_f32_16x16x32_bf16(af1, bw[1][1], a1, 0,0,0); \
    a2 = __builtin_amdgcn_mfma_f32_16x16x32_bf16(af1, bw[2][1], a2, 0,0,0); \
    a3 = __builtin_amdgcn_mfma_f32_16x16x32_bf16(af1, bw[3][1], a3, 0,0,0); \
    a0 = __builtin_amdgcn_mfma_f32_16x16x32_bf16(af2, bw[0][2], a0, 0,0,0); \
    a1 = __builtin_amdgcn_mfma_f32_16x16x32_bf16(af2, bw[1][2], a1, 0,0,0); \
    a2 = __builtin_amdgcn_mfma_f32_16x16x32_bf16(af2, bw[2][2], a2, 0,0,0); \
    a3 = __builtin_amdgcn_mfma_f32_16x16x32_bf16(af2, bw[3][2], a3, 0,0,0); \
    a0 = __builtin_amdgcn_mfma_f32_16x16x32_bf16(af3, bw[0][3], a0, 0,0,0); \
    a1 = __builtin_amdgcn_mfma_f32_16x16x32_bf16(af3, bw[1][3], a1, 0,0,0); \
    a2 = __builtin_amdgcn_mfma_f32_16x16x32_bf16(af3, bw[2][3], a2, 0,0,0); \
    a3 = __builtin_amdgcn_mfma_f32_16x16x32_bf16(af3, bw[3][3], a3, 0,0,0); \
    if (hi == 0){ \
      *(f32x4*)(PrL +         jm4) = a0; \
      *(f32x4*)(PrL +  512 + jm4) = a1; \
      *(f32x4*)(PrL + 1024 + jm4) = a2; \
      *(f32x4*)(PrL + 1536 + jm4) = a3; \
    } \
    wg_barrier(); \
    float pa0 = PrL[        prIdx]; \
    float pa1 = PrL[ 512 + prIdx]; \
    float pa2 = PrL[1024 + prIdx]; \
    float pa3 = PrL[1536 + prIdx]; \
    float xi = pa0 + (bf2f((uint16_t)GXR[0]) + biasB0); \
    float xf = pa1 + (bf2f((uint16_t)GXR[1]) + biasB1); \
    float xg = pa2 + (bf2f((uint16_t)GXR[2]) + biasB2); \
    float xo = pa3 + (bf2f((uint16_t)GXR[3]) + biasB3); \
    GXR = *(const bf16x4*)gptr; gptr += 2048; \
    float iv = sigm(xi), fv = sigm(xf), gv = tanh_(xg), ov = sigm(xo); \
    cst = fv * cst + iv * gv; \
    float hval = ov * tanh_(cst); \
    uint16_t hbf = f2bf(hval); \
    *(uint16_t*)(hwb) = hbf; \
    if (!last){ \
      Aout[aoutBase + (size_t)(tcur)*H_] = hbf; \
    } else if ((tcur) == T_-1){ \
      hlast[(b0+bB)*H_ + jB] = hval; \
    } \
    wg_barrier(); \
  } while(0)

__global__ __launch_bounds__(512) void scan_kernel(const uint16_t* __restrict__ GXb,
      const uint16_t* __restrict__ Whh, const float* __restrict__ bsum,
      uint16_t* __restrict__ Aout, float* __restrict__ hlast, int last){
  __shared__ uint16_t hTile[4*128];     // row b: byte b*256 + ((j*2) ^ (b<<4))
  __shared__ float    PrL[4*512];       // [g][j][b] : g*512 + j*4 + b
  int tid = threadIdx.x;
  int w = tid >> 6, l = tid & 63, lo = l & 15, hi = l >> 4;
  int jm = w*16 + lo;                   // MFMA output column (0..127)
  int bB = tid >> 7, jB = tid & 127;    // phase-B (batch,col) ownership
  int b0 = blockIdx.x * 4;

  bf16x8 bw[4][4];
#pragma unroll
  for (int g = 0; g < 4; ++g)
#pragma unroll
    for (int kc = 0; kc < 4; ++kc)
      bw[g][kc] = *(const bf16x8*)(Whh + (g*128 + jm)*H_ + kc*32 + hi*8);

  float biasB0 = bsum[      jB];
  float biasB1 = bsum[128 + jB];
  float biasB2 = bsum[256 + jB];
  float biasB3 = bsum[384 + jB];
  float cst = 0.0f;

  const char* hbase = (const char*)hTile;
  int afo0 = lo*256 + (( 0  + hi*16) ^ (lo << 4));
  int afo1 = lo*256 + (( 64 + hi*16) ^ (lo << 4));
  int afo2 = lo*256 + ((128 + hi*16) ^ (lo << 4));
  int afo3 = lo*256 + ((192 + hi*16) ^ (lo << 4));
  int jm4 = jm*4;
  int prIdx = jB*4 + bB;
  char* hwb = (char*)hTile + bB*256 + ((jB*2) ^ (bB << 4));
  size_t aoutBase = (size_t)(b0+bB)*T_*H_ + jB;

  const uint16_t* gptr = GXb + (size_t)blockIdx.x * T_ * 2048 + bB*512 + jB*4;
  bf16x4 ga, gb, gc, gd;
  ga = *(const bf16x4*)(gptr);        gptr += 2048;
  gb = *(const bf16x4*)(gptr);        gptr += 2048;
  gc = *(const bf16x4*)(gptr);        gptr += 2048;
  gd = *(const bf16x4*)(gptr);        gptr += 2048;

  hTile[tid < 512 ? tid : 0] = 0;
  __syncthreads();

  const bf16x8 Z8 = {0,0,0,0,0,0,0,0};
  const f32x4  z4 = {0.f,0.f,0.f,0.f};

  for (int t = 0; t < T_; t += 4){
    STEP(t,   ga);
    STEP(t+1, gb);
    STEP(t+2, gc);
    STEP(t+3, gd);
  }
}

// ---------------------------------------------------------------- final MLP (fp32)
__global__ void mlp_kernel(const float* __restrict__ hlast,
    const float* __restrict__ w1, const float* __restrict__ b1,
    const float* __restrict__ w2, const float* __restrict__ b2,
    const float* __restrict__ w3, const float* __restrict__ b3,
    float* __restrict__ out){
  int b = blockIdx.x, t = threadIdx.x;
  __shared__ float sh[128];
  __shared__ float s1[64];
  __shared__ float s2[32];
  sh[t] = hlast[b*H_ + t];
  sh[t+64] = hlast[b*H_ + t + 64];
  __syncthreads();
  if (t < 64){
    float d = b1[t];
    for (int k = 0; k < 128; ++k) d += sh[k]*w1[t*128+k];
    s1[t] = d;
  }
  __syncthreads();
  if (t < 32){
    float d = b2[t];
    for (int k = 0; k < 64; ++k) d += s1[k]*w2[t*64+k];
    s2[t] = d;
  }
  __syncthreads();
  if (t < 10){
    float d = b3[t];
    for (int k = 0; k < 32; ++k) d += s2[k]*w3[t*32+k];
    out[b*OUT_ + t] = d;
  }
}

// ---------------------------------------------------------------- launch
extern "C" void kernel_launch(void* const* d_in, const int* in_sizes, int n_in,
                              void* d_out, int out_size, void* d_ws, size_t ws_size,
                              hipStream_t stream){
  const float* x   = (const float*)d_in[0];
  const float* wih = (const float*)d_in[1];
  const float* whh = (const float*)d_in[2];
  const float* bih = (const float*)d_in[3];
  const float* bhh = (const float*)d_in[4];
  const float* w1  = (const float*)d_in[5];
  const float* b1  = (const float*)d_in[6];
  const float* w2  = (const float*)d_in[7];
  const float* b2  = (const float*)d_in[8];
  const float* w3  = (const float*)d_in[9];
  const float* b3  = (const float*)d_in[10];
  float* out = (float*)d_out;

  char* ws = (char*)d_ws;
  uint16_t* A0   = (uint16_t*)(ws);                     // B*T*H bf16   = 33554432 B
  uint16_t* A1   = (uint16_t*)(ws + 33554432);          // B*T*H bf16   = 33554432 B
  uint16_t* GXb  = (uint16_t*)(ws + 67108864);          // B*T*G bf16   = 134217728 B (+64KB pad)
  uint16_t* WIH  = (uint16_t*)(ws + 201392128);         // 3*512*128 bf16
  uint16_t* WHH  = (uint16_t*)(ws + 201785344);         // 3*512*128 bf16
  float*    BSUM = (float*)   (ws + 202178560);         // 3*512 f32
  float*    HL   = (float*)   (ws + 202184704);         // 64*128 f32

  prep_kernel<<<2048, 256, 0, stream>>>(x, wih, whh, bih, bhh, A0, WIH, WHH, BSUM);

  const uint16_t* ain[3] = {A0, A1, A0};
  uint16_t*       aout[3] = {A1, A0, A1};
  for (int lyr = 0; lyr < 3; ++lyr){
    proj_kernel<<<512, 512, 0, stream>>>(ain[lyr], WIH + lyr*G_*H_, GXb);
    scan_kernel<<<16, 512, 0, stream>>>(GXb, WHH + lyr*G_*H_, BSUM + lyr*G_,
                                        aout[lyr], HL, lyr == 2 ? 1 : 0);
  }
  mlp_kernel<<<B_, 64, 0, stream>>>(HL, w1, b1, w2, b2, w3, b3, out);
}

// Round 4
// 2930.899 us; speedup vs baseline: 2.1819x; 1.6224x over previous
//
#include <hip/hip_runtime.h>
#include <stdint.h>

#define B_ 64
#define T_ 2048
#define H_ 128
#define G_ 512
#define NL 3
#define OUT_ 10

typedef __attribute__((ext_vector_type(8))) short bf16x8;
typedef __attribute__((ext_vector_type(4))) short bf16x4;
typedef __attribute__((ext_vector_type(4))) float f32x4;

__device__ __forceinline__ float bf2f(uint16_t u){
  union { uint32_t u; float f; } v; v.u = ((uint32_t)u) << 16; return v.f;
}
__device__ __forceinline__ uint16_t f2bf(float f){
  union { float f; uint32_t u; } v; v.f = f;
  uint32_t u = v.u;
  uint32_t r = (u + 0x7FFFu + ((u >> 16) & 1u)) >> 16;
  return (uint16_t)r;
}

// Barrier WITHOUT vmcnt(0) drain: LDS ordering only; global loads/stores
// stay in flight across steps.
__device__ __forceinline__ void wg_barrier(){
  asm volatile("s_waitcnt lgkmcnt(0)" ::: "memory");
  __builtin_amdgcn_sched_barrier(0);
  __builtin_amdgcn_s_barrier();
  __builtin_amdgcn_sched_barrier(0);
}

// ---------------------------------------------------------------- prep
// WHH is pre-scaled per gate: i,f,o rows * -log2(e), g rows * 2*log2(e),
// so gates become rcp(1+exp2(x)) with no per-step multiply.
__global__ void prep_kernel(const float* __restrict__ x,
                            const float* __restrict__ wih, const float* __restrict__ whh,
                            const float* __restrict__ bih, const float* __restrict__ bhh,
                            uint16_t* __restrict__ A0, uint16_t* __restrict__ WIH,
                            uint16_t* __restrict__ WHH, float* __restrict__ BSUM){
  int stride = gridDim.x * blockDim.x;
  int g0 = blockIdx.x * blockDim.x + threadIdx.x;
  for (int i = g0; i < B_*T_*H_; i += stride) A0[i] = f2bf(x[i]);
  for (int i = g0; i < NL*G_*H_; i += stride){
    WIH[i] = f2bf(wih[i]);
    int n = (i >> 7) & 511;                 // row within layer
    float sc = ((n >> 7) == 2) ? 2.88539008f : -1.44269504f;
    WHH[i] = f2bf(whh[i] * sc);
  }
  for (int i = g0; i < NL*G_; i += stride) BSUM[i] = bih[i] + bhh[i];
}

// ---------------------------------------------------------------- projection GEMM
// gx[b][t][n] = sum_k Ain[b][t][k]*W[n][k]; epilogue: (acc + bias)*scale(g),
// written bf16 to GXc[(b>>2)*T*2048 + t*2048 + (b&3)*512 + j*4 + g], n=g*128+j.
__global__ __launch_bounds__(512) void proj_kernel(const uint16_t* __restrict__ Ain,
      const uint16_t* __restrict__ W, const float* __restrict__ bsum,
      uint16_t* __restrict__ GXc){
  __shared__ uint16_t Alds[16*128];
  int tid = threadIdx.x;
  int w = tid >> 6, l = tid & 63, lo = l & 15, hi = l >> 4;
  int n0 = w * 64;
  bf16x8 bw[4][4];
  float bsv[4], scv[4];
#pragma unroll
  for (int nt = 0; nt < 4; ++nt){
    int n = n0 + nt*16 + lo;
#pragma unroll
    for (int kc = 0; kc < 4; ++kc)
      bw[nt][kc] = *(const bf16x8*)(W + n*H_ + kc*32 + hi*8);
    bsv[nt] = bsum[n];
    scv[nt] = ((n >> 7) == 2) ? 2.88539008f : -1.44269504f;
  }
  for (int m = blockIdx.x; m < (B_*T_)/16; m += gridDim.x){
    if (tid < 256){
      int row = tid >> 4, c16 = tid & 15;
      f32x4 v = *(const f32x4*)(Ain + (size_t)(m*16 + row)*H_ + c16*8);
      *(f32x4*)((char*)Alds + row*256 + ((c16*16) ^ ((row & 7) << 4))) = v;
    }
    __syncthreads();
    bf16x8 af[4];
#pragma unroll
    for (int kc = 0; kc < 4; ++kc)
      af[kc] = *(const bf16x8*)((const char*)Alds + lo*256 + (((kc*64) + hi*16) ^ ((lo & 7) << 4)));
    f32x4 acc[4];
#pragma unroll
    for (int nt = 0; nt < 4; ++nt)
#pragma unroll
      for (int r = 0; r < 4; ++r) acc[nt][r] = 0.0f;
#pragma unroll
    for (int kc = 0; kc < 4; ++kc)
#pragma unroll
      for (int nt = 0; nt < 4; ++nt)
        acc[nt] = __builtin_amdgcn_mfma_f32_16x16x32_bf16(af[kc], bw[nt][kc], acc[nt], 0, 0, 0);
    int b  = m >> 7;            // 128 tiles per batch
    int t0 = (m & 127) << 4;
    size_t base = (size_t)(b >> 2) * T_ * 2048 + (size_t)(b & 3) * 512;
#pragma unroll
    for (int nt = 0; nt < 4; ++nt){
      int n = n0 + nt*16 + lo;
      int g = n >> 7, jj = n & 127;
#pragma unroll
      for (int r = 0; r < 4; ++r){
        int t = t0 + hi*4 + r;
        GXc[base + (size_t)t*2048 + jj*4 + g] = f2bf((acc[nt][r] + bsv[nt]) * scv[nt]);
      }
    }
    __syncthreads();
  }
}

// ---------------------------------------------------------------- scan
// 16 WGs x 512 thr, 4 batches/WG. Duplicate-row trick: A-frag rows 4..15 are
// copies of rows 0..3, so EVERY lane (hi,lo) holds pre-acts of cell
// (b=r, j=w*16+lo) in a_g[r]. Lane picks r=hi via 3 cndmask per gate:
// 512 threads = 512 real cells, 1 barrier/step, no LDS redistribution.
#define STEP(tcur, GXR, RB, WB) do { \
    bf16x8 af0 = *(const bf16x8*)((const char*)(RB) + afo0); \
    bf16x8 af1 = *(const bf16x8*)((const char*)(RB) + afo1); \
    bf16x8 af2 = *(const bf16x8*)((const char*)(RB) + afo2); \
    bf16x8 af3 = *(const bf16x8*)((const char*)(RB) + afo3); \
    f32x4 a0, a1, a2, a3; \
    a0 = __builtin_amdgcn_mfma_f32_16x16x32_bf16(af0, bw[0][0], z4, 0,0,0); \
    a1 = __builtin_amdgcn_mfma_f32_16x16x32_bf16(af0, bw[1][0], z4, 0,0,0); \
    a2 = __builtin_amdgcn_mfma_f32_16x16x32_bf16(af0, bw[2][0], z4, 0,0,0); \
    a3 = __builtin_amdgcn_mfma_f32_16x16x32_bf16(af0, bw[3][0], z4, 0,0,0); \
    a0 = __builtin_amdgcn_mfma_f32_16x16x32_bf16(af1, bw[0][1], a0, 0,0,0); \
    a1 = __builtin_amdgcn_mfma_f32_16x16x32_bf16(af1, bw[1][1], a1, 0,0,0); \
    a2 = __builtin_amdgcn_mfma_f32_16x16x32_bf16(af1, bw[2][1], a2, 0,0,0); \
    a3 = __builtin_amdgcn_mfma_f32_16x16x32_bf16(af1, bw[3][1], a3, 0,0,0); \
    a0 = __builtin_amdgcn_mfma_f32_16x16x32_bf16(af2, bw[0][2], a0, 0,0,0); \
    a1 = __builtin_amdgcn_mfma_f32_16x16x32_bf16(af2, bw[1][2], a1, 0,0,0); \
    a2 = __builtin_amdgcn_mfma_f32_16x16x32_bf16(af2, bw[2][2], a2, 0,0,0); \
    a3 = __builtin_amdgcn_mfma_f32_16x16x32_bf16(af2, bw[3][2], a3, 0,0,0); \
    a0 = __builtin_amdgcn_mfma_f32_16x16x32_bf16(af3, bw[0][3], a0, 0,0,0); \
    a1 = __builtin_amdgcn_mfma_f32_16x16x32_bf16(af3, bw[1][3], a1, 0,0,0); \
    a2 = __builtin_amdgcn_mfma_f32_16x16x32_bf16(af3, bw[2][3], a2, 0,0,0); \
    a3 = __builtin_amdgcn_mfma_f32_16x16x32_bf16(af3, bw[3][3], a3, 0,0,0); \
    float p0 = hiB1 ? a0[1] : a0[0]; float q0 = hiB1 ? a0[3] : a0[2]; \
    float p1 = hiB1 ? a1[1] : a1[0]; float q1 = hiB1 ? a1[3] : a1[2]; \
    float p2 = hiB1 ? a2[1] : a2[0]; float q2 = hiB1 ? a2[3] : a2[2]; \
    float p3 = hiB1 ? a3[1] : a3[0]; float q3 = hiB1 ? a3[3] : a3[2]; \
    float x0 = (hiB2 ? q0 : p0) + bf2f((uint16_t)GXR[0]); \
    float x1 = (hiB2 ? q1 : p1) + bf2f((uint16_t)GXR[1]); \
    float x2 = (hiB2 ? q2 : p2) + bf2f((uint16_t)GXR[2]); \
    float x3 = (hiB2 ? q3 : p3) + bf2f((uint16_t)GXR[3]); \
    GXR = *(const bf16x4*)gptr; gptr += 2048; \
    float iv = __builtin_amdgcn_rcpf(1.0f + __builtin_amdgcn_exp2f(x0)); \
    float fv = __builtin_amdgcn_rcpf(1.0f + __builtin_amdgcn_exp2f(x1)); \
    float gt = __builtin_amdgcn_rcpf(1.0f + __builtin_amdgcn_exp2f(x2)); \
    float ov = __builtin_amdgcn_rcpf(1.0f + __builtin_amdgcn_exp2f(x3)); \
    float gv = __builtin_fmaf(-2.0f, gt, 1.0f); \
    cst = fv * cst + iv * gv; \
    float tt = __builtin_amdgcn_rcpf(1.0f + __builtin_amdgcn_exp2f(2.88539008f * cst)); \
    float th = __builtin_fmaf(-2.0f, tt, 1.0f); \
    float hval = ov * th; \
    uint32_t hp; \
    asm("v_cvt_pk_bf16_f32 %0, %1, %2" : "=v"(hp) : "v"(hval), "v"(hval)); \
    *(uint16_t*)((char*)(WB) + hw_off) = (uint16_t)hp; \
    if (!last){ \
      Aout[aoutBase + (size_t)(tcur)*H_] = (uint16_t)hp; \
    } else if ((tcur) == T_-1){ \
      hlast[(b0+hi)*H_ + j] = hval; \
    } \
    wg_barrier(); \
  } while(0)

__global__ __launch_bounds__(512) void scan_kernel(const uint16_t* __restrict__ GXc,
      const uint16_t* __restrict__ Whhs,
      uint16_t* __restrict__ Aout, float* __restrict__ hlast, int last){
  __shared__ uint16_t hb0[4*128];
  __shared__ uint16_t hb1[4*128];
  int tid = threadIdx.x;
  int w = tid >> 6, l = tid & 63, lo = l & 15, hi = l >> 4;
  int j = w*16 + lo;
  int b0 = blockIdx.x * 4;
  bool hiB1 = (hi & 1), hiB2 = (hi & 2);

  bf16x8 bw[4][4];
#pragma unroll
  for (int g = 0; g < 4; ++g)
#pragma unroll
    for (int kc = 0; kc < 4; ++kc)
      bw[g][kc] = *(const bf16x8*)(Whhs + (g*128 + j)*H_ + kc*32 + hi*8);

  // A-frag read offsets: row rb = lo&3, swizzle bits 5-6 by row.
  int rb = lo & 3;
  int swr = ((rb & 1) << 6) | ((rb >> 1) << 5);
  int afo0 = rb*256 + ((  0 + hi*16) ^ swr);
  int afo1 = rb*256 + (( 64 + hi*16) ^ swr);
  int afo2 = rb*256 + ((128 + hi*16) ^ swr);
  int afo3 = rb*256 + ((192 + hi*16) ^ swr);
  // h write: cell (b=hi, j)
  int hw_off = hi*256 + ((j*2) ^ (((hi & 1) << 6) | ((hi >> 1) << 5)));
  size_t aoutBase = (size_t)(b0 + hi) * T_ * H_ + j;

  float cst = 0.0f;
  const uint16_t* gptr = GXc + (size_t)blockIdx.x * T_ * 2048 + hi*512 + j*4;
  bf16x4 ga, gb, gc, gd;
  ga = *(const bf16x4*)gptr; gptr += 2048;
  gb = *(const bf16x4*)gptr; gptr += 2048;
  gc = *(const bf16x4*)gptr; gptr += 2048;
  gd = *(const bf16x4*)gptr; gptr += 2048;

  hb0[tid] = 0;
  hb1[tid] = 0;
  __syncthreads();

  const f32x4 z4 = {0.f,0.f,0.f,0.f};

  for (int t = 0; t < T_; t += 4){
    STEP(t,   ga, hb0, hb1);
    STEP(t+1, gb, hb1, hb0);
    STEP(t+2, gc, hb0, hb1);
    STEP(t+3, gd, hb1, hb0);
  }
}

// ---------------------------------------------------------------- final MLP (fp32)
__global__ void mlp_kernel(const float* __restrict__ hlast,
    const float* __restrict__ w1, const float* __restrict__ b1,
    const float* __restrict__ w2, const float* __restrict__ b2,
    const float* __restrict__ w3, const float* __restrict__ b3,
    float* __restrict__ out){
  int b = blockIdx.x, t = threadIdx.x;
  __shared__ float sh[128];
  __shared__ float s1[64];
  __shared__ float s2[32];
  sh[t] = hlast[b*H_ + t];
  sh[t+64] = hlast[b*H_ + t + 64];
  __syncthreads();
  if (t < 64){
    float d = b1[t];
    for (int k = 0; k < 128; ++k) d += sh[k]*w1[t*128+k];
    s1[t] = d;
  }
  __syncthreads();
  if (t < 32){
    float d = b2[t];
    for (int k = 0; k < 64; ++k) d += s1[k]*w2[t*64+k];
    s2[t] = d;
  }
  __syncthreads();
  if (t < 10){
    float d = b3[t];
    for (int k = 0; k < 32; ++k) d += s2[k]*w3[t*32+k];
    out[b*OUT_ + t] = d;
  }
}

// ---------------------------------------------------------------- launch
extern "C" void kernel_launch(void* const* d_in, const int* in_sizes, int n_in,
                              void* d_out, int out_size, void* d_ws, size_t ws_size,
                              hipStream_t stream){
  const float* x   = (const float*)d_in[0];
  const float* wih = (const float*)d_in[1];
  const float* whh = (const float*)d_in[2];
  const float* bih = (const float*)d_in[3];
  const float* bhh = (const float*)d_in[4];
  const float* w1  = (const float*)d_in[5];
  const float* b1  = (const float*)d_in[6];
  const float* w2  = (const float*)d_in[7];
  const float* b2  = (const float*)d_in[8];
  const float* w3  = (const float*)d_in[9];
  const float* b3  = (const float*)d_in[10];
  float* out = (float*)d_out;

  char* ws = (char*)d_ws;
  uint16_t* A0   = (uint16_t*)(ws);                     // B*T*H bf16   = 33554432 B
  uint16_t* A1   = (uint16_t*)(ws + 33554432);          // B*T*H bf16   = 33554432 B
  uint16_t* GXc  = (uint16_t*)(ws + 67108864);          // B*T*G bf16   = 134217728 B (+64KB pad)
  uint16_t* WIH  = (uint16_t*)(ws + 201392128);         // 3*512*128 bf16
  uint16_t* WHH  = (uint16_t*)(ws + 201785344);         // 3*512*128 bf16 (pre-scaled)
  float*    BSUM = (float*)   (ws + 202178560);         // 3*512 f32
  float*    HL   = (float*)   (ws + 202184704);         // 64*128 f32

  prep_kernel<<<2048, 256, 0, stream>>>(x, wih, whh, bih, bhh, A0, WIH, WHH, BSUM);

  const uint16_t* ain[3] = {A0, A1, A0};
  uint16_t*       aout[3] = {A1, A0, A1};
  for (int lyr = 0; lyr < 3; ++lyr){
    proj_kernel<<<512, 512, 0, stream>>>(ain[lyr], WIH + lyr*G_*H_, BSUM + lyr*G_, GXc);
    scan_kernel<<<16, 512, 0, stream>>>(GXc, WHH + lyr*G_*H_,
                                        aout[lyr], HL, lyr == 2 ? 1 : 0);
  }
  mlp_kernel<<<B_, 64, 0, stream>>>(HL, w1, b1, w2, b2, w3, b3, out);
}

// Round 5
// 2090.228 us; speedup vs baseline: 3.0594x; 1.4022x over previous
//
#include <hip/hip_runtime.h>
#include <stdint.h>

#define B_ 64
#define T_ 2048
#define H_ 128
#define G_ 512
#define NL 3
#define OUT_ 10
#define CHK 16
#define NCH (T_/CHK)

typedef __attribute__((ext_vector_type(8))) short bf16x8;
typedef __attribute__((ext_vector_type(4))) float f32x4;

#define MF(A,BW,C) __builtin_amdgcn_mfma_f32_16x16x32_bf16(A,BW,C,0,0,0)

__device__ __forceinline__ uint16_t f2bf(float f){
  union { float f; uint32_t u; } v; v.f = f;
  uint32_t u = v.u;
  uint32_t r = (u + 0x7FFFu + ((u >> 16) & 1u)) >> 16;
  return (uint16_t)r;
}

// Barrier WITHOUT vmcnt(0) drain: LDS ordering only.
__device__ __forceinline__ void wg_barrier(){
  asm volatile("s_waitcnt lgkmcnt(0)" ::: "memory");
  __builtin_amdgcn_sched_barrier(0);
  __builtin_amdgcn_s_barrier();
  __builtin_amdgcn_sched_barrier(0);
}

// ---------------------------------------------------------------- prep
// Both weight matrices pre-scaled per gate (i,f,o: -log2e; g: +2*log2e) so
// gates become rcp(1+exp2(x)). Bias likewise pre-scaled (folded into MFMA C).
__global__ void prep_kernel(const float* __restrict__ x,
                            const float* __restrict__ wih, const float* __restrict__ whh,
                            const float* __restrict__ bih, const float* __restrict__ bhh,
                            uint16_t* __restrict__ A0, uint16_t* __restrict__ WIHS,
                            uint16_t* __restrict__ WHHS, float* __restrict__ BSCL,
                            int* __restrict__ flags){
  int stride = gridDim.x * blockDim.x;
  int g0 = blockIdx.x * blockDim.x + threadIdx.x;
  for (int i = g0; i < B_*T_*H_; i += stride) A0[i] = f2bf(x[i]);
  for (int i = g0; i < NL*G_*H_; i += stride){
    int n = (i >> 7) & 511;
    float sc = ((n >> 7) == 2) ? 2.88539008f : -1.44269504f;
    WIHS[i] = f2bf(wih[i] * sc);
    WHHS[i] = f2bf(whh[i] * sc);
  }
  for (int i = g0; i < NL*G_; i += stride){
    float sc = (((i & 511) >> 7) == 2) ? 2.88539008f : -1.44269504f;
    BSCL[i] = (bih[i] + bhh[i]) * sc;
  }
  if (g0 < 32) flags[g0] = 0;
}

// ---------------------------------------------------------------- fused pipelined scan
// 48 WGs: layer = wg/16, q = wg%16 (4 batches). Per step: 16 gx MFMAs
// (x@Wih, independent, computed one step ahead) + 16 rec MFMAs (h@Whh with
// C = gx+bias) + duplicate-row select + gates. Layer l hands h to layer l+1
// in K=16-step chunks via release/acquire flags; consumer stays 2 chunks
// behind so its 2-step x-prefetch never races the producer.
#define STEPF(tcur, AXL, AXU, GCC, GCN, RB, WB) do { \
    bf16x8 af0 = *(const bf16x8*)((const char*)(RB) + afo0); \
    bf16x8 af1 = *(const bf16x8*)((const char*)(RB) + afo1); \
    bf16x8 af2 = *(const bf16x8*)((const char*)(RB) + afo2); \
    bf16x8 af3 = *(const bf16x8*)((const char*)(RB) + afo3); \
    f32x4 a0 = MF(af0, bwhh[0][0], GCC[0]); \
    f32x4 a1 = MF(af0, bwhh[1][0], GCC[1]); \
    f32x4 a2 = MF(af0, bwhh[2][0], GCC[2]); \
    f32x4 a3 = MF(af0, bwhh[3][0], GCC[3]); \
    a0 = MF(af1, bwhh[0][1], a0); a1 = MF(af1, bwhh[1][1], a1); \
    a2 = MF(af1, bwhh[2][1], a2); a3 = MF(af1, bwhh[3][1], a3); \
    a0 = MF(af2, bwhh[0][2], a0); a1 = MF(af2, bwhh[1][2], a1); \
    a2 = MF(af2, bwhh[2][2], a2); a3 = MF(af2, bwhh[3][2], a3); \
    a0 = MF(af3, bwhh[0][3], a0); a1 = MF(af3, bwhh[1][3], a1); \
    a2 = MF(af3, bwhh[2][3], a2); a3 = MF(af3, bwhh[3][3], a3); \
    { int tc_ = (tcur) + 2; tc_ = tc_ > T_-1 ? T_-1 : tc_; \
      const uint16_t* xb_ = Xin + (size_t)tc_ * H_; \
      AXL[0] = *(const bf16x8*)(xb_ + xo0); \
      AXL[1] = *(const bf16x8*)(xb_ + xo1); \
      AXL[2] = *(const bf16x8*)(xb_ + xo2); \
      AXL[3] = *(const bf16x8*)(xb_ + xo3); } \
    GCN[0] = MF(AXU[0], bwih[0][0], binit0); \
    GCN[1] = MF(AXU[0], bwih[1][0], binit1); \
    GCN[2] = MF(AXU[0], bwih[2][0], binit2); \
    GCN[3] = MF(AXU[0], bwih[3][0], binit3); \
    GCN[0] = MF(AXU[1], bwih[0][1], GCN[0]); GCN[1] = MF(AXU[1], bwih[1][1], GCN[1]); \
    GCN[2] = MF(AXU[1], bwih[2][1], GCN[2]); GCN[3] = MF(AXU[1], bwih[3][1], GCN[3]); \
    GCN[0] = MF(AXU[2], bwih[0][2], GCN[0]); GCN[1] = MF(AXU[2], bwih[1][2], GCN[1]); \
    GCN[2] = MF(AXU[2], bwih[2][2], GCN[2]); GCN[3] = MF(AXU[2], bwih[3][2], GCN[3]); \
    GCN[0] = MF(AXU[3], bwih[0][3], GCN[0]); GCN[1] = MF(AXU[3], bwih[1][3], GCN[1]); \
    GCN[2] = MF(AXU[3], bwih[2][3], GCN[2]); GCN[3] = MF(AXU[3], bwih[3][3], GCN[3]); \
    float p0 = hiB1 ? a0[1] : a0[0]; float q0 = hiB1 ? a0[3] : a0[2]; \
    float p1 = hiB1 ? a1[1] : a1[0]; float q1 = hiB1 ? a1[3] : a1[2]; \
    float p2 = hiB1 ? a2[1] : a2[0]; float q2 = hiB1 ? a2[3] : a2[2]; \
    float p3 = hiB1 ? a3[1] : a3[0]; float q3 = hiB1 ? a3[3] : a3[2]; \
    float x0 = hiB2 ? q0 : p0; \
    float x1 = hiB2 ? q1 : p1; \
    float x2 = hiB2 ? q2 : p2; \
    float x3 = hiB2 ? q3 : p3; \
    float iv = __builtin_amdgcn_rcpf(1.0f + __builtin_amdgcn_exp2f(x0)); \
    float fv = __builtin_amdgcn_rcpf(1.0f + __builtin_amdgcn_exp2f(x1)); \
    float gt = __builtin_amdgcn_rcpf(1.0f + __builtin_amdgcn_exp2f(x2)); \
    float ov = __builtin_amdgcn_rcpf(1.0f + __builtin_amdgcn_exp2f(x3)); \
    float gv = __builtin_fmaf(-2.0f, gt, 1.0f); \
    cst = fv * cst + iv * gv; \
    float tt = __builtin_amdgcn_rcpf(1.0f + __builtin_amdgcn_exp2f(2.88539008f * cst)); \
    float th = __builtin_fmaf(-2.0f, tt, 1.0f); \
    float hval = ov * th; \
    uint32_t hp; \
    asm("v_cvt_pk_bf16_f32 %0, %1, %2" : "=v"(hp) : "v"(hval), "v"(hval)); \
    *(uint16_t*)((char*)(WB) + hw_off) = (uint16_t)hp; \
    if (layer < 2){ \
      Hout[houtBase + (size_t)(tcur)*H_] = (uint16_t)hp; \
    } else if ((tcur) == T_-1){ \
      hlast[(b0+hi)*H_ + j] = hval; \
    } \
    wg_barrier(); \
  } while(0)

__global__ __launch_bounds__(512, 2) void fused_kernel(
    const uint16_t* __restrict__ A0, uint16_t* __restrict__ H1,
    uint16_t* __restrict__ H2, const uint16_t* __restrict__ WIHS,
    const uint16_t* __restrict__ WHHS, const float* __restrict__ BSCL,
    float* __restrict__ hlast, int* __restrict__ flags){
  __shared__ uint16_t hb0[4*128];
  __shared__ uint16_t hb1[4*128];
  int tid = threadIdx.x;
  int wg = blockIdx.x;
  int layer = wg >> 4, q = wg & 15;
  int b0 = q * 4;
  int w = tid >> 6, l = tid & 63, lo = l & 15, hi = l >> 4;
  int j = w*16 + lo;
  bool hiB1 = (hi & 1), hiB2 = (hi & 2);

  const uint16_t* Xin = (layer == 0) ? A0 : ((layer == 1) ? H1 : H2);
  uint16_t* Hout = (layer == 0) ? H1 : H2;   // unused for layer 2
  int* flgP = flags + layer*16 + q;          // producer flag (layer<2)
  int* flgC = flags + (layer-1)*16 + q;      // consumer flag (layer>0)

  const uint16_t* wihL = WIHS + layer*G_*H_;
  const uint16_t* whhL = WHHS + layer*G_*H_;

  bf16x8 bwih[4][4], bwhh[4][4];
#pragma unroll
  for (int g = 0; g < 4; ++g)
#pragma unroll
    for (int kc = 0; kc < 4; ++kc){
      bwih[g][kc] = *(const bf16x8*)(wihL + (g*128 + j)*H_ + kc*32 + hi*8);
      bwhh[g][kc] = *(const bf16x8*)(whhL + (g*128 + j)*H_ + kc*32 + hi*8);
    }
  float bs0 = BSCL[layer*G_ +       j];
  float bs1 = BSCL[layer*G_ + 128 + j];
  float bs2 = BSCL[layer*G_ + 256 + j];
  float bs3 = BSCL[layer*G_ + 384 + j];
  f32x4 binit0 = {bs0,bs0,bs0,bs0};
  f32x4 binit1 = {bs1,bs1,bs1,bs1};
  f32x4 binit2 = {bs2,bs2,bs2,bs2};
  f32x4 binit3 = {bs3,bs3,bs3,bs3};

  // A-frag h-tile offsets (R4-verified swizzle, 0 bank conflicts)
  int rb = lo & 3;
  int swr = ((rb & 1) << 6) | ((rb >> 1) << 5);
  int afo0 = rb*256 + ((  0 + hi*16) ^ swr);
  int afo1 = rb*256 + (( 64 + hi*16) ^ swr);
  int afo2 = rb*256 + ((128 + hi*16) ^ swr);
  int afo3 = rb*256 + ((192 + hi*16) ^ swr);
  int hw_off = hi*256 + ((j*2) ^ (((hi & 1) << 6) | ((hi >> 1) << 5)));
  size_t houtBase = (size_t)(b0 + hi) * T_ * H_ + j;

  // x A-frag global offsets (row rb duplicated across lo groups)
  int xo0 = (b0 + rb)*T_*H_ +  0*32 + hi*8;
  int xo1 = (b0 + rb)*T_*H_ +  1*32 + hi*8;
  int xo2 = (b0 + rb)*T_*H_ +  2*32 + hi*8;
  int xo3 = (b0 + rb)*T_*H_ +  3*32 + hi*8;

  float cst = 0.0f;
  hb0[tid] = 0;
  hb1[tid] = 0;

  if (layer > 0 && tid == 0){
    while (__hip_atomic_load(flgC, __ATOMIC_ACQUIRE, __HIP_MEMORY_SCOPE_AGENT) < 2)
      __builtin_amdgcn_s_sleep(8);
  }
  __syncthreads();

  bf16x8 axA[4], axB[4];
  {
    const uint16_t* xb = Xin;          // t = 0
    axA[0] = *(const bf16x8*)(xb + xo0);
    axA[1] = *(const bf16x8*)(xb + xo1);
    axA[2] = *(const bf16x8*)(xb + xo2);
    axA[3] = *(const bf16x8*)(xb + xo3);
    xb = Xin + H_;                     // t = 1
    axB[0] = *(const bf16x8*)(xb + xo0);
    axB[1] = *(const bf16x8*)(xb + xo1);
    axB[2] = *(const bf16x8*)(xb + xo2);
    axB[3] = *(const bf16x8*)(xb + xo3);
  }
  f32x4 gE[4], gO[4];
  gE[0] = MF(axA[0], bwih[0][0], binit0);
  gE[1] = MF(axA[0], bwih[1][0], binit1);
  gE[2] = MF(axA[0], bwih[2][0], binit2);
  gE[3] = MF(axA[0], bwih[3][0], binit3);
#pragma unroll
  for (int kc = 1; kc < 4; ++kc){
    gE[0] = MF(axA[kc], bwih[0][kc], gE[0]);
    gE[1] = MF(axA[kc], bwih[1][kc], gE[1]);
    gE[2] = MF(axA[kc], bwih[2][kc], gE[2]);
    gE[3] = MF(axA[kc], bwih[3][kc], gE[3]);
  }

  for (int c = 0; c < NCH; ++c){
    int tb = c * CHK;
#pragma unroll
    for (int kk = 0; kk < 4; ++kk){
      int t = tb + kk*4;
      STEPF(t,   axA, axB, gE, gO, hb0, hb1);
      STEPF(t+1, axB, axA, gO, gE, hb1, hb0);
      STEPF(t+2, axA, axB, gE, gO, hb0, hb1);
      STEPF(t+3, axB, axA, gO, gE, hb1, hb0);
    }
    if (layer < 2){
      asm volatile("s_waitcnt vmcnt(0)" ::: "memory");
      __syncthreads();
      if (tid == 0)
        __hip_atomic_store(flgP, c + 1, __ATOMIC_RELEASE, __HIP_MEMORY_SCOPE_AGENT);
    }
    if (layer > 0 && c + 1 < NCH){
      int target = c + 3; if (target > NCH) target = NCH;
      if (tid == 0){
        while (__hip_atomic_load(flgC, __ATOMIC_ACQUIRE, __HIP_MEMORY_SCOPE_AGENT) < target)
          __builtin_amdgcn_s_sleep(8);
      }
      __syncthreads();
    }
  }
}

// ---------------------------------------------------------------- final MLP (fp32)
__global__ void mlp_kernel(const float* __restrict__ hlast,
    const float* __restrict__ w1, const float* __restrict__ b1,
    const float* __restrict__ w2, const float* __restrict__ b2,
    const float* __restrict__ w3, const float* __restrict__ b3,
    float* __restrict__ out){
  int b = blockIdx.x, t = threadIdx.x;
  __shared__ float sh[128];
  __shared__ float s1[64];
  __shared__ float s2[32];
  sh[t] = hlast[b*H_ + t];
  sh[t+64] = hlast[b*H_ + t + 64];
  __syncthreads();
  if (t < 64){
    float d = b1[t];
    for (int k = 0; k < 128; ++k) d += sh[k]*w1[t*128+k];
    s1[t] = d;
  }
  __syncthreads();
  if (t < 32){
    float d = b2[t];
    for (int k = 0; k < 64; ++k) d += s1[k]*w2[t*64+k];
    s2[t] = d;
  }
  __syncthreads();
  if (t < 10){
    float d = b3[t];
    for (int k = 0; k < 32; ++k) d += s2[k]*w3[t*32+k];
    out[b*OUT_ + t] = d;
  }
}

// ---------------------------------------------------------------- launch
extern "C" void kernel_launch(void* const* d_in, const int* in_sizes, int n_in,
                              void* d_out, int out_size, void* d_ws, size_t ws_size,
                              hipStream_t stream){
  const float* x   = (const float*)d_in[0];
  const float* wih = (const float*)d_in[1];
  const float* whh = (const float*)d_in[2];
  const float* bih = (const float*)d_in[3];
  const float* bhh = (const float*)d_in[4];
  const float* w1  = (const float*)d_in[5];
  const float* b1  = (const float*)d_in[6];
  const float* w2  = (const float*)d_in[7];
  const float* b2  = (const float*)d_in[8];
  const float* w3  = (const float*)d_in[9];
  const float* b3  = (const float*)d_in[10];
  float* out = (float*)d_out;

  char* ws = (char*)d_ws;
  uint16_t* A0   = (uint16_t*)(ws);                     // 33554432 B
  uint16_t* H1   = (uint16_t*)(ws + 33554432);          // 33554432 B
  uint16_t* H2   = (uint16_t*)(ws + 67108864);          // 33554432 B
  uint16_t* WIHS = (uint16_t*)(ws + 100663296);         // 393216 B
  uint16_t* WHHS = (uint16_t*)(ws + 101056512);         // 393216 B
  float*    BSCL = (float*)   (ws + 101449728);         // 6144 B
  float*    HL   = (float*)   (ws + 101455872);         // 32768 B
  int*      FLG  = (int*)     (ws + 101488640);         // 128 B

  prep_kernel<<<2048, 256, 0, stream>>>(x, wih, whh, bih, bhh, A0, WIHS, WHHS, BSCL, FLG);
  fused_kernel<<<48, 512, 0, stream>>>(A0, H1, H2, WIHS, WHHS, BSCL, HL, FLG);
  mlp_kernel<<<B_, 64, 0, stream>>>(HL, w1, b1, w2, b2, w3, b3, out);
}

// Round 9
// 2085.289 us; speedup vs baseline: 3.0667x; 1.0024x over previous
//
#include <hip/hip_runtime.h>
#include <stdint.h>

#define B_ 64
#define T_ 2048
#define H_ 128
#define G_ 512
#define NL 3
#define OUT_ 10
#define CHK 16
#define NCH (T_/CHK)

typedef __attribute__((ext_vector_type(8))) short bf16x8;
typedef __attribute__((ext_vector_type(4))) float f32x4;

#define MF(A,BW,C) __builtin_amdgcn_mfma_f32_16x16x32_bf16(A,BW,C,0,0,0)

__device__ __forceinline__ uint16_t f2bf(float f){
  union { float f; uint32_t u; } v; v.f = f;
  uint32_t u = v.u;
  uint32_t r = (u + 0x7FFFu + ((u >> 16) & 1u)) >> 16;
  return (uint16_t)r;
}

// Barrier WITHOUT vmcnt(0) drain: LDS ordering only.
__device__ __forceinline__ void wg_barrier(){
  asm volatile("s_waitcnt lgkmcnt(0)" ::: "memory");
  __builtin_amdgcn_sched_barrier(0);
  __builtin_amdgcn_s_barrier();
  __builtin_amdgcn_sched_barrier(0);
}

// ---------------------------------------------------------------- prep
// Weights pre-scaled per gate (i,f,o: -log2e; g: +2*log2e) so gates become
// rcp(1+exp2(x)); bias likewise pre-scaled (folded into MFMA C-init).
__global__ void prep_kernel(const float* __restrict__ x,
                            const float* __restrict__ wih, const float* __restrict__ whh,
                            const float* __restrict__ bih, const float* __restrict__ bhh,
                            uint16_t* __restrict__ A0, uint16_t* __restrict__ WIHS,
                            uint16_t* __restrict__ WHHS, float* __restrict__ BSCL,
                            int* __restrict__ flags){
  int stride = gridDim.x * blockDim.x;
  int g0 = blockIdx.x * blockDim.x + threadIdx.x;
  for (int i = g0; i < B_*T_*H_; i += stride) A0[i] = f2bf(x[i]);
  for (int i = g0; i < NL*G_*H_; i += stride){
    int n = (i >> 7) & 511;
    float sc = ((n >> 7) == 2) ? 2.88539008f : -1.44269504f;
    WIHS[i] = f2bf(wih[i] * sc);
    WHHS[i] = f2bf(whh[i] * sc);
  }
  for (int i = g0; i < NL*G_; i += stride){
    float sc = (((i & 511) >> 7) == 2) ? 2.88539008f : -1.44269504f;
    BSCL[i] = (bih[i] + bhh[i]) * sc;
  }
  if (g0 < 32) flags[g0] = 0;
}

// ---------------------------------------------------------------- fused pipelined scan
// 48 WGs: layer = wg/16, q = wg%16 (4 batches). Per step: 16 gx MFMAs
// (x@Wih, independent, computed one step ahead) + 16 rec MFMAs (h@Whh with
// C = gx+bias) + duplicate-row select + gates. Layer l hands h to layer l+1
// in K=16-step chunks via release/acquire flags; consumer stays 2 chunks
// behind so its 2-step x-prefetch never races the producer.
// R9 change vs R5: bwhh pinned in registers (asm opaque) so the compiler
// cannot rematerialize rec-path weight loads onto the serial critical path.
#define STEPF(tcur, AXL, AXU, GCC, GCN) do { \
    bf16x8 af0 = *(const bf16x8*)((const char*)RBp + afo0); \
    bf16x8 af1 = *(const bf16x8*)((const char*)RBp + afo1); \
    bf16x8 af2 = *(const bf16x8*)((const char*)RBp + afo2); \
    bf16x8 af3 = *(const bf16x8*)((const char*)RBp + afo3); \
    f32x4 a0 = MF(af0, bwhh[0][0], GCC[0]); \
    f32x4 a1 = MF(af0, bwhh[1][0], GCC[1]); \
    f32x4 a2 = MF(af0, bwhh[2][0], GCC[2]); \
    f32x4 a3 = MF(af0, bwhh[3][0], GCC[3]); \
    a0 = MF(af1, bwhh[0][1], a0); a1 = MF(af1, bwhh[1][1], a1); \
    a2 = MF(af1, bwhh[2][1], a2); a3 = MF(af1, bwhh[3][1], a3); \
    a0 = MF(af2, bwhh[0][2], a0); a1 = MF(af2, bwhh[1][2], a1); \
    a2 = MF(af2, bwhh[2][2], a2); a3 = MF(af2, bwhh[3][2], a3); \
    a0 = MF(af3, bwhh[0][3], a0); a1 = MF(af3, bwhh[1][3], a1); \
    a2 = MF(af3, bwhh[2][3], a2); a3 = MF(af3, bwhh[3][3], a3); \
    { int tc_ = (tcur) + 2; tc_ = tc_ > T_-1 ? T_-1 : tc_; \
      const uint16_t* xb_ = Xin + (size_t)tc_ * H_; \
      AXL[0] = *(const bf16x8*)(xb_ + xo0); \
      AXL[1] = *(const bf16x8*)(xb_ + xo1); \
      AXL[2] = *(const bf16x8*)(xb_ + xo2); \
      AXL[3] = *(const bf16x8*)(xb_ + xo3); } \
    GCN[0] = MF(AXU[0], bwih[0][0], binit0); \
    GCN[1] = MF(AXU[0], bwih[1][0], binit1); \
    GCN[2] = MF(AXU[0], bwih[2][0], binit2); \
    GCN[3] = MF(AXU[0], bwih[3][0], binit3); \
    GCN[0] = MF(AXU[1], bwih[0][1], GCN[0]); GCN[1] = MF(AXU[1], bwih[1][1], GCN[1]); \
    GCN[2] = MF(AXU[1], bwih[2][1], GCN[2]); GCN[3] = MF(AXU[1], bwih[3][1], GCN[3]); \
    GCN[0] = MF(AXU[2], bwih[0][2], GCN[0]); GCN[1] = MF(AXU[2], bwih[1][2], GCN[1]); \
    GCN[2] = MF(AXU[2], bwih[2][2], GCN[2]); GCN[3] = MF(AXU[2], bwih[3][2], GCN[3]); \
    GCN[0] = MF(AXU[3], bwih[0][3], GCN[0]); GCN[1] = MF(AXU[3], bwih[1][3], GCN[1]); \
    GCN[2] = MF(AXU[3], bwih[2][3], GCN[2]); GCN[3] = MF(AXU[3], bwih[3][3], GCN[3]); \
    float p0 = hiB1 ? a0[1] : a0[0]; float q0 = hiB1 ? a0[3] : a0[2]; \
    float p1 = hiB1 ? a1[1] : a1[0]; float q1 = hiB1 ? a1[3] : a1[2]; \
    float p2 = hiB1 ? a2[1] : a2[0]; float q2 = hiB1 ? a2[3] : a2[2]; \
    float p3 = hiB1 ? a3[1] : a3[0]; float q3 = hiB1 ? a3[3] : a3[2]; \
    float x0 = hiB2 ? q0 : p0; \
    float x1 = hiB2 ? q1 : p1; \
    float x2 = hiB2 ? q2 : p2; \
    float x3 = hiB2 ? q3 : p3; \
    float iv = __builtin_amdgcn_rcpf(1.0f + __builtin_amdgcn_exp2f(x0)); \
    float fv = __builtin_amdgcn_rcpf(1.0f + __builtin_amdgcn_exp2f(x1)); \
    float gt = __builtin_amdgcn_rcpf(1.0f + __builtin_amdgcn_exp2f(x2)); \
    float ov = __builtin_amdgcn_rcpf(1.0f + __builtin_amdgcn_exp2f(x3)); \
    float gv = __builtin_fmaf(-2.0f, gt, 1.0f); \
    cst = fv * cst + iv * gv; \
    float tt = __builtin_amdgcn_rcpf(1.0f + __builtin_amdgcn_exp2f(2.88539008f * cst)); \
    float th = __builtin_fmaf(-2.0f, tt, 1.0f); \
    float hval = ov * th; \
    uint32_t hp; \
    asm("v_cvt_pk_bf16_f32 %0, %1, %2" : "=v"(hp) : "v"(hval), "v"(hval)); \
    *(uint16_t*)((char*)WBp + hw_off) = (uint16_t)hp; \
    if (layer < 2){ \
      Hout[houtBase + (size_t)(tcur)*H_] = (uint16_t)hp; \
    } else if ((tcur) == T_-1){ \
      hlast[(b0+hi)*H_ + j] = hval; \
    } \
    wg_barrier(); \
    { uint16_t* tmp_ = RBp; RBp = WBp; WBp = tmp_; } \
  } while(0)

__global__ __launch_bounds__(512, 2) void fused_kernel(
    const uint16_t* __restrict__ A0, uint16_t* __restrict__ H1,
    uint16_t* __restrict__ H2, const uint16_t* __restrict__ WIHS,
    const uint16_t* __restrict__ WHHS, const float* __restrict__ BSCL,
    float* __restrict__ hlast, int* __restrict__ flags){
  __shared__ uint16_t hb0[4*128];
  __shared__ uint16_t hb1[4*128];
  int tid = threadIdx.x;
  int wg = blockIdx.x;
  int layer = wg >> 4, q = wg & 15;
  int b0 = q * 4;
  int w = tid >> 6, l = tid & 63, lo = l & 15, hi = l >> 4;
  int j = w*16 + lo;
  bool hiB1 = (hi & 1), hiB2 = (hi & 2);

  const uint16_t* Xin = (layer == 0) ? A0 : ((layer == 1) ? H1 : H2);
  uint16_t* Hout = (layer == 0) ? H1 : H2;   // unused for layer 2
  int* flgP = flags + layer*16 + q;          // producer flag (layer<2)
  int* flgC = flags + (layer-1)*16 + q;      // consumer flag (layer>0)

  const uint16_t* wihL = WIHS + layer*G_*H_;
  const uint16_t* whhL = WHHS + layer*G_*H_;

  bf16x8 bwih[4][4], bwhh[4][4];
#pragma unroll
  for (int g = 0; g < 4; ++g)
#pragma unroll
    for (int kc = 0; kc < 4; ++kc){
      bwih[g][kc] = *(const bf16x8*)(wihL + (g*128 + j)*H_ + kc*32 + hi*8);
      bwhh[g][kc] = *(const bf16x8*)(whhL + (g*128 + j)*H_ + kc*32 + hi*8);
    }
  // Pin ONLY the rec-path weights: opaque to the compiler -> cannot be
  // rematerialized as per-step L2 reloads on the serial h(t) critical path.
  // (bwih left rematerializable: gx MFMAs are a step ahead, latency-tolerant;
  //  pinning both would push VGPRs past 256 and spill.)
#pragma unroll
  for (int g = 0; g < 4; ++g)
#pragma unroll
    for (int kc = 0; kc < 4; ++kc)
      asm volatile("" : "+v"(bwhh[g][kc]));

  float bs0 = BSCL[layer*G_ +       j];
  float bs1 = BSCL[layer*G_ + 128 + j];
  float bs2 = BSCL[layer*G_ + 256 + j];
  float bs3 = BSCL[layer*G_ + 384 + j];
  f32x4 binit0 = {bs0,bs0,bs0,bs0};
  f32x4 binit1 = {bs1,bs1,bs1,bs1};
  f32x4 binit2 = {bs2,bs2,bs2,bs2};
  f32x4 binit3 = {bs3,bs3,bs3,bs3};

  // A-frag h-tile offsets (R4-verified swizzle, 0 bank conflicts)
  int rb = lo & 3;
  int swr = ((rb & 1) << 6) | ((rb >> 1) << 5);
  int afo0 = rb*256 + ((  0 + hi*16) ^ swr);
  int afo1 = rb*256 + (( 64 + hi*16) ^ swr);
  int afo2 = rb*256 + ((128 + hi*16) ^ swr);
  int afo3 = rb*256 + ((192 + hi*16) ^ swr);
  int hw_off = hi*256 + ((j*2) ^ (((hi & 1) << 6) | ((hi >> 1) << 5)));
  size_t houtBase = (size_t)(b0 + hi) * T_ * H_ + j;

  // x A-frag global offsets (row rb duplicated across lo groups)
  int xo0 = (b0 + rb)*T_*H_ +  0*32 + hi*8;
  int xo1 = (b0 + rb)*T_*H_ +  1*32 + hi*8;
  int xo2 = (b0 + rb)*T_*H_ +  2*32 + hi*8;
  int xo3 = (b0 + rb)*T_*H_ +  3*32 + hi*8;

  float cst = 0.0f;
  hb0[tid] = 0;
  hb1[tid] = 0;

  if (layer > 0 && tid == 0){
    while (__hip_atomic_load(flgC, __ATOMIC_ACQUIRE, __HIP_MEMORY_SCOPE_AGENT) < 2)
      __builtin_amdgcn_s_sleep(8);
  }
  __syncthreads();

  bf16x8 axA[4], axB[4];
  {
    const uint16_t* xb = Xin;          // t = 0
    axA[0] = *(const bf16x8*)(xb + xo0);
    axA[1] = *(const bf16x8*)(xb + xo1);
    axA[2] = *(const bf16x8*)(xb + xo2);
    axA[3] = *(const bf16x8*)(xb + xo3);
    xb = Xin + H_;                     // t = 1
    axB[0] = *(const bf16x8*)(xb + xo0);
    axB[1] = *(const bf16x8*)(xb + xo1);
    axB[2] = *(const bf16x8*)(xb + xo2);
    axB[3] = *(const bf16x8*)(xb + xo3);
  }
  f32x4 gE[4], gO[4];
  gE[0] = MF(axA[0], bwih[0][0], binit0);
  gE[1] = MF(axA[0], bwih[1][0], binit1);
  gE[2] = MF(axA[0], bwih[2][0], binit2);
  gE[3] = MF(axA[0], bwih[3][0], binit3);
#pragma unroll
  for (int kc = 1; kc < 4; ++kc){
    gE[0] = MF(axA[kc], bwih[0][kc], gE[0]);
    gE[1] = MF(axA[kc], bwih[1][kc], gE[1]);
    gE[2] = MF(axA[kc], bwih[2][kc], gE[2]);
    gE[3] = MF(axA[kc], bwih[3][kc], gE[3]);
  }

  uint16_t* RBp = hb0;
  uint16_t* WBp = hb1;

  for (int c = 0; c < NCH; ++c){
    int tb = c * CHK;
#pragma unroll
    for (int kk = 0; kk < 4; ++kk){
      int t = tb + kk*4;
      STEPF(t,   axA, axB, gE, gO);
      STEPF(t+1, axB, axA, gO, gE);
      STEPF(t+2, axA, axB, gE, gO);
      STEPF(t+3, axB, axA, gO, gE);
    }
    if (layer < 2){
      asm volatile("s_waitcnt vmcnt(0)" ::: "memory");
      __syncthreads();
      if (tid == 0)
        __hip_atomic_store(flgP, c + 1, __ATOMIC_RELEASE, __HIP_MEMORY_SCOPE_AGENT);
    }
    if (layer > 0 && c + 1 < NCH){
      int target = c + 3; if (target > NCH) target = NCH;
      if (tid == 0){
        while (__hip_atomic_load(flgC, __ATOMIC_ACQUIRE, __HIP_MEMORY_SCOPE_AGENT) < target)
          __builtin_amdgcn_s_sleep(8);
      }
      __syncthreads();
    }
  }
}

// ---------------------------------------------------------------- final MLP (fp32)
__global__ void mlp_kernel(const float* __restrict__ hlast,
    const float* __restrict__ w1, const float* __restrict__ b1,
    const float* __restrict__ w2, const float* __restrict__ b2,
    const float* __restrict__ w3, const float* __restrict__ b3,
    float* __restrict__ out){
  int b = blockIdx.x, t = threadIdx.x;
  __shared__ float sh[128];
  __shared__ float s1[64];
  __shared__ float s2[32];
  sh[t] = hlast[b*H_ + t];
  sh[t+64] = hlast[b*H_ + t + 64];
  __syncthreads();
  if (t < 64){
    float d = b1[t];
    for (int k = 0; k < 128; ++k) d += sh[k]*w1[t*128+k];
    s1[t] = d;
  }
  __syncthreads();
  if (t < 32){
    float d = b2[t];
    for (int k = 0; k < 64; ++k) d += s1[k]*w2[t*64+k];
    s2[t] = d;
  }
  __syncthreads();
  if (t < 10){
    float d = b3[t];
    for (int k = 0; k < 32; ++k) d += s2[k]*w3[t*32+k];
    out[b*OUT_ + t] = d;
  }
}

// ---------------------------------------------------------------- launch
extern "C" void kernel_launch(void* const* d_in, const int* in_sizes, int n_in,
                              void* d_out, int out_size, void* d_ws, size_t ws_size,
                              hipStream_t stream){
  const float* x   = (const float*)d_in[0];
  const float* wih = (const float*)d_in[1];
  const float* whh = (const float*)d_in[2];
  const float* bih = (const float*)d_in[3];
  const float* bhh = (const float*)d_in[4];
  const float* w1  = (const float*)d_in[5];
  const float* b1  = (const float*)d_in[6];
  const float* w2  = (const float*)d_in[7];
  const float* b2  = (const float*)d_in[8];
  const float* w3  = (const float*)d_in[9];
  const float* b3  = (const float*)d_in[10];
  float* out = (float*)d_out;

  char* ws = (char*)d_ws;
  uint16_t* A0   = (uint16_t*)(ws);                     // 33554432 B
  uint16_t* H1   = (uint16_t*)(ws + 33554432);          // 33554432 B
  uint16_t* H2   = (uint16_t*)(ws + 67108864);          // 33554432 B
  uint16_t* WIHS = (uint16_t*)(ws + 100663296);         // 393216 B
  uint16_t* WHHS = (uint16_t*)(ws + 101056512);         // 393216 B
  float*    BSCL = (float*)   (ws + 101449728);         // 6144 B
  float*    HL   = (float*)   (ws + 101455872);         // 32768 B
  int*      FLG  = (int*)     (ws + 101488640);         // 128 B

  prep_kernel<<<2048, 256, 0, stream>>>(x, wih, whh, bih, bhh, A0, WIHS, WHHS, BSCL, FLG);
  fused_kernel<<<48, 512, 0, stream>>>(A0, H1, H2, WIHS, WHHS, BSCL, HL, FLG);
  mlp_kernel<<<B_, 64, 0, stream>>>(HL, w1, b1, w2, b2, w3, b3, out);
}